// Round 6
// baseline (336.324 us; speedup 1.0000x reference)
//
#include <hip/hip_runtime.h>
#include <stdint.h>

#define TOKENS 8192
#define INF    4096
#define OUTF   4096
#define RANK   256

#define BM   32     // tokens per block
#define BK   64     // phase-1 K per tile  (64 tiles)
#define BN2  64     // phase-2 outf per tile (64 tiles)
#define NT   64

typedef __attribute__((ext_vector_type(8))) short bf16x8;
typedef __attribute__((ext_vector_type(4))) float f32x4;

// ---- LDS layout (ushort units), total 61440 ush = 122880 B ----
// V/U tile bufs: 3 x 16384 (32 KB each)  [phase1: V 256r x 64k bf16;
//                                         phase2: U 64r x 256k bf16]
// x bufs:        3 x 4096  (8 KB each)   [32 tok x 64 k fp32]
// T[32][256] bf16 (8192 ush) overlays x bufs 0-1 between phases.
#define VOFF(i) ((i) * 16384)
#define XOFF(i) (49152 + (i) * 4096)
#define TOFF    49152
#define SMSZ    61440

#define WAITV5 asm volatile("s_waitcnt vmcnt(5)" ::: "memory")
#define WAITV0 asm volatile("s_waitcnt vmcnt(0)" ::: "memory")
#define BAR    __builtin_amdgcn_s_barrier()

__device__ __forceinline__ unsigned short f2bf(float f) {
    union { float f; unsigned int u; } v; v.f = f;
    unsigned int r = v.u + 0x7FFFu + ((v.u >> 16) & 1u);   // RNE
    return (unsigned short)(r >> 16);
}

__device__ __forceinline__ unsigned cvtpk(float lo, float hi) {
    unsigned r;
    asm("v_cvt_pk_bf16_f32 %0, %1, %2" : "=v"(r) : "v"(lo), "v"(hi));
    return r;   // low16 = bf16(lo), high16 = bf16(hi)
}

__device__ __forceinline__ void gl_lds16(const void* g, void* l) {
    __builtin_amdgcn_global_load_lds(
        (const __attribute__((address_space(1))) unsigned int*)g,
        (__attribute__((address_space(3))) unsigned int*)l, 16, 0, 0);
}

// ---------------- fp32 -> bf16 convert (V then U, one launch) --------------
__global__ void cvt4(const float4* __restrict__ va, ushort4* __restrict__ oa, int na,
                     const float4* __restrict__ vb, ushort4* __restrict__ ob) {
    int i = blockIdx.x * blockDim.x + threadIdx.x;
    float4 v;
    if (i < na) v = va[i]; else v = vb[i - na];
    ushort4 o;
    o.x = f2bf(v.x); o.y = f2bf(v.y); o.z = f2bf(v.z); o.w = f2bf(v.w);
    if (i < na) oa[i] = o; else ob[i - na] = o;
}

// ---------------- fused: out = (x @ V^T) @ U^T + bias ----------------
// 256 blocks x 512 thr (8 waves), 1 block/CU.
// Pipeline: 3-deep LDS buffers, counted s_waitcnt vmcnt(5) + raw s_barrier
// per tile (T3+T4): tile t's 5 staging loads retire at the wait, tile t+1's
// stay in flight across the barrier. Never drains to 0 in steady state.
// vmcnt ledger (phase 1): per tile stage = 4 V gl_lds + 1 x gl_lds = 5.
//   At wait@t, everything issued after stage(t) is >= tile t+1's 5 instrs,
//   so vmcnt(5) retires stage(t) regardless of intra-tile reordering.
// vmcnt ledger (phase 2): per tile = 1 bias + 4 U gl_lds + 1 store = 6 >= 6
//   instrs separate stage(t) from wait@t -> vmcnt(5) safe. Bias is consumed
//   2 tiles after load so its compiler wait can't drain the stage queue.

__global__ __launch_bounds__(512, 2) void fused(const float* __restrict__ x,
                                                const unsigned short* __restrict__ Vb,
                                                const unsigned short* __restrict__ Ub,
                                                const float* __restrict__ bias,
                                                float* __restrict__ out) {
    __shared__ __align__(16) unsigned short SM[SMSZ];

    const int tid  = threadIdx.x;
    const int lane = tid & 63;
    const int wid  = tid >> 6;            // 0..7
    const int m0   = blockIdx.x * BM;
    const int l15  = lane & 15;
    const int quad = lane >> 4;
    const int sw8  = l15 & 7;

    // ---- staging lane maps (computed once) ----
    // V: wave stages its own rows wid*32..+31; 4 x gl_lds16, 8 rows each.
    const int vrow_j = (lane >> 3);            // row-in-group 0..7
    const int vsc    = lane & 7;               // chunk 0..7 (16B units)
    // x: wave stages rows wid*4..+3 (fp32); 1 x gl_lds16, 4 rows.
    const int xrow   = wid * 4 + (lane >> 4);
    const int xsc    = (lane & 15) ^ (xrow & 7);
    // U: wave stages rows wid*8..+7; 4 x gl_lds16, 2 rows each.
    const int urow_j = (lane >> 5);            // 0..1
    const int usc    = lane & 31;

    f32x4 acc[2][2];
    #pragma unroll
    for (int i = 0; i < 2; ++i)
        #pragma unroll
        for (int j = 0; j < 2; ++j) acc[i][j] = (f32x4){0.f, 0.f, 0.f, 0.f};

    // ================= phase 1: T = x @ V^T =================
    auto stageV = [&](int t, int bo) {
        const int kk = t * BK;
        #pragma unroll
        for (int j = 0; j < 4; ++j) {
            int row = wid * 32 + j * 8 + vrow_j;
            int c   = vsc ^ (row & 7);
            gl_lds16(Vb + (size_t)row * INF + kk + c * 8,
                     &SM[VOFF(bo) + (wid * 32 + j * 8) * BK]);
        }
    };
    auto stageX = [&](int t, int bo) {
        const int kk = t * BK;
        gl_lds16(x + (size_t)(m0 + xrow) * INF + kk + xsc * 4,
                 &SM[XOFF(bo) + wid * 512]);
    };
    auto compute1 = [&](int bo) {
        const unsigned short* vb = &SM[VOFF(bo)];
        const float* xb = (const float*)&SM[XOFF(bo)];
        const int rr0 = wid * 32 + l15;
        #pragma unroll
        for (int ks = 0; ks < 2; ++ks) {
            int pv = ((ks * 4 + quad) ^ sw8) * 8;
            bf16x8 v0 = *(const bf16x8*)&vb[rr0 * BK + pv];
            bf16x8 v1 = *(const bf16x8*)&vb[(rr0 + 16) * BK + pv];
            #pragma unroll
            for (int mt = 0; mt < 2; ++mt) {
                int tok = mt * 16 + l15;
                int c0  = ks * 8 + quad * 2;
                f32x4 lo = *(const f32x4*)&xb[tok * 64 + ((c0    ) ^ sw8) * 4];
                f32x4 hi = *(const f32x4*)&xb[tok * 64 + ((c0 + 1) ^ sw8) * 4];
                union { unsigned u[4]; bf16x8 v; } pk;
                pk.u[0] = cvtpk(lo[0], lo[1]); pk.u[1] = cvtpk(lo[2], lo[3]);
                pk.u[2] = cvtpk(hi[0], hi[1]); pk.u[3] = cvtpk(hi[2], hi[3]);
                acc[0][mt] = __builtin_amdgcn_mfma_f32_16x16x32_bf16(v0, pk.v, acc[0][mt], 0, 0, 0);
                acc[1][mt] = __builtin_amdgcn_mfma_f32_16x16x32_bf16(v1, pk.v, acc[1][mt], 0, 0, 0);
            }
        }
    };

    // prologue: tiles 0,1 staged (10 loads in flight)
    stageV(0, 0); stageX(0, 0);
    stageV(1, 1); stageX(1, 1);

    {
        int cb = 0, sb = 2;
        #pragma unroll 1
        for (int t = 0; t < NT - 2; ++t) {
            WAITV5;                      // retire stage(t); keep stage(t+1)
            BAR;                         // all waves' stage(t) LDS-visible
            stageV(t + 2, sb); stageX(t + 2, sb);
            compute1(cb);
            cb = (cb == 2) ? 0 : cb + 1;
            sb = (sb == 2) ? 0 : sb + 1;
        }
        WAITV5; BAR; compute1(2);        // tile 62 (62%3==2)
        WAITV0; BAR; compute1(0);        // tile 63 (63%3==0), full drain once
    }

    // ================= transition: acc -> T (LDS) -> tf regs =================
    __syncthreads();                     // all phase-1 LDS reads done
    // acc[mv][mx]: lane holds ranks wid*32+mv*16+quad*4+{0..3} of tok mx*16+l15
    #pragma unroll
    for (int mv = 0; mv < 2; ++mv)
        #pragma unroll
        for (int mx = 0; mx < 2; ++mx) {
            int tok = mx * 16 + l15;
            int cc  = wid * 4 + mv * 2 + (quad >> 1);  // 16B chunk of rank row
            int sc  = cc ^ sw8;
            union { unsigned u[2]; ushort4 s; } o;
            o.u[0] = cvtpk(acc[mv][mx][0], acc[mv][mx][1]);
            o.u[1] = cvtpk(acc[mv][mx][2], acc[mv][mx][3]);
            *(ushort4*)&SM[TOFF + tok * RANK + sc * 8 + (quad & 1) * 4] = o.s;
        }

    auto stageU = [&](int t, int bo) {
        const int nb = t * BN2;
        #pragma unroll
        for (int j = 0; j < 4; ++j) {
            int row = wid * 8 + j * 2 + urow_j;
            int sc  = usc ^ (row & 7);
            gl_lds16(Ub + (size_t)(nb + row) * RANK + sc * 8,
                     &SM[VOFF(bo) + (wid * 8 + j * 2) * RANK]);
        }
    };
    stageU(0, 0); stageU(1, 1);

    const int wy = wid & 1;              // token half
    const int wx = wid >> 1;             // outf quarter within tile
    const int tok2 = wy * 16 + l15;
    const int biascol = wx * 16 + quad * 4;

    // bias pipeline, 2 tiles deep (issued here; drained by the syncthreads)
    float4 bbA = *(const float4*)&bias[0 * BN2 + biascol];
    float4 bbB = *(const float4*)&bias[1 * BN2 + biascol];

    __syncthreads();                     // T visible; U(0),U(1) drained (once)

    bf16x8 tf[8];
    #pragma unroll
    for (int ks = 0; ks < 8; ++ks)
        tf[ks] = *(const bf16x8*)
            &SM[TOFF + tok2 * RANK + (((ks * 4 + quad) ^ sw8) * 8)];

    // ================= phase 2: out = T @ U^T + bias =================
    const size_t orow = (size_t)(m0 + tok2) * OUTF;
    const int ur = wx * 16 + l15;

    {
        int cb = 0, sb = 2;
        #pragma unroll 1
        for (int t = 0; t < NT - 1; ++t) {
            WAITV5;                      // retire stage(t) (>=6 vmem since)
            BAR;
            float4 bnew = make_float4(0.f, 0.f, 0.f, 0.f);
            if (t + 2 < NT)
                bnew = *(const float4*)&bias[(t + 2) * BN2 + biascol];
            if (t + 2 < NT) stageU(t + 2, sb);
            const unsigned short* ub = &SM[VOFF(cb)];
            f32x4 a2 = (f32x4){0.f, 0.f, 0.f, 0.f};
            #pragma unroll
            for (int ks = 0; ks < 8; ++ks) {
                bf16x8 uf = *(const bf16x8*)
                    &ub[ur * RANK + (((ks * 4 + quad) ^ sw8) * 8)];
                a2 = __builtin_amdgcn_mfma_f32_16x16x32_bf16(uf, tf[ks], a2, 0, 0, 0);
            }
            int nc = t * BN2 + biascol;
            float4 v;
            v.x = a2[0] + bbA.x; v.y = a2[1] + bbA.y;
            v.z = a2[2] + bbA.z; v.w = a2[3] + bbA.w;
            *(float4*)&out[orow + nc] = v;
            bbA = bbB; bbB = bnew;
            cb = (cb == 2) ? 0 : cb + 1;
            sb = (sb == 2) ? 0 : sb + 1;
        }
        // tile 63 (63%3==0): full drain once
        WAITV0; BAR;
        const unsigned short* ub = &SM[VOFF(0)];
        f32x4 a2 = (f32x4){0.f, 0.f, 0.f, 0.f};
        #pragma unroll
        for (int ks = 0; ks < 8; ++ks) {
            bf16x8 uf = *(const bf16x8*)
                &ub[ur * RANK + (((ks * 4 + quad) ^ sw8) * 8)];
            a2 = __builtin_amdgcn_mfma_f32_16x16x32_bf16(uf, tf[ks], a2, 0, 0, 0);
        }
        int nc = (NT - 1) * BN2 + biascol;
        float4 v;
        v.x = a2[0] + bbA.x; v.y = a2[1] + bbA.y;
        v.z = a2[2] + bbA.z; v.w = a2[3] + bbA.w;
        *(float4*)&out[orow + nc] = v;
    }
}

extern "C" void kernel_launch(void* const* d_in, const int* in_sizes, int n_in,
                              void* d_out, int out_size, void* d_ws, size_t ws_size,
                              hipStream_t stream) {
    const float* x    = (const float*)d_in[0];
    const float* U    = (const float*)d_in[1];
    const float* V    = (const float*)d_in[2];
    const float* bias = (const float*)d_in[3];
    float* out = (float*)d_out;

    // ws layout: Vb (2MB) | Ub (2MB)
    unsigned short* Vb = (unsigned short*)d_ws;
    unsigned short* Ub = Vb + (size_t)RANK * INF;

    const int nv = RANK * INF / 4;
    const int nu = OUTF * RANK / 4;
    cvt4<<<(nv + nu) / 256, 256, 0, stream>>>((const float4*)V, (ushort4*)Vb, nv,
                                              (const float4*)U, (ushort4*)Ub);
    fused<<<TOKENS / BM, 512, 0, stream>>>(x, Vb, Ub, bias, out);
}